// Round 2
// baseline (315.181 us; speedup 1.0000x reference)
//
#include <hip/hip_runtime.h>
#include <hip/hip_bf16.h>
#include <stdint.h>

typedef short bf16x8 __attribute__((ext_vector_type(8)));
typedef float f32x4 __attribute__((ext_vector_type(4)));
typedef __attribute__((address_space(3))) void lds_void_t;
typedef __attribute__((address_space(1))) void g_void_t;

static __device__ __forceinline__ unsigned short f2b(float f) {
    __hip_bfloat16 b = __float2bfloat16(f);
    return __builtin_bit_cast(unsigned short, b);
}
static __device__ __forceinline__ float b2f(unsigned int u) {
    return __builtin_bit_cast(float, u << 16);
}

// ---------------- cast fp32 -> bf16, vectorized ----------------
__global__ __launch_bounds__(256) void cast_f32_bf16(
    const float* __restrict__ in, ushort* __restrict__ out, int n4)
{
    int i = blockIdx.x * blockDim.x + threadIdx.x;
    const int stride = gridDim.x * blockDim.x;
    for (; i < n4; i += stride) {
        float4 v = reinterpret_cast<const float4*>(in)[i];
        ushort4 o;
        o.x = f2b(v.x); o.y = f2b(v.y); o.z = f2b(v.z); o.w = f2b(v.w);
        reinterpret_cast<ushort4*>(out)[i] = o;
    }
}

// ---------------- 128x128 bf16 GEMM, C = (A * B^T + bias) * alpha ---------
// A: [M][lda] bf16 (K contiguous), B: [N][ldb] bf16 (K contiguous)
// grid: (N/128, M/128, batch); block 256 (4 waves, 2x2 wave grid)
template<typename CT, bool HAS_BIAS>
__global__ __launch_bounds__(256, 2)
void gemm_bt(const ushort* __restrict__ A, const ushort* __restrict__ B,
             const float* __restrict__ bias, CT* __restrict__ C,
             int lda, int ldb, int ldc, int K,
             long strideA, long strideB, long strideC, float alpha)
{
    __shared__ __align__(16) ushort sA[128 * 64];
    __shared__ __align__(16) ushort sB[128 * 64];

    const int bz = blockIdx.z;
    A += (size_t)bz * strideA;
    B += (size_t)bz * strideB;
    C += (size_t)bz * strideC;

    const int tid = threadIdx.x;
    const int w   = tid >> 6;
    const int l   = tid & 63;
    const int wr  = w >> 1;
    const int wc  = w & 1;

    const int bRow = blockIdx.y * 128;
    const int bCol = blockIdx.x * 128;

    // staging: each wave covers 8 chunks (4 for A, 4 for B), chunk = 1KB = 8 rows.
    // LDS holds the XOR-swizzled layout: LDS[row][slot16] = global[row][slot16 ^ (row&7)].
    // Achieved by pre-swizzling the per-lane GLOBAL source (linear LDS dest).
    const int lr   = l >> 3;                    // row within 8-row chunk
    const int scol = (((l & 7) ^ lr) << 3);     // swizzled source col (elems)

    f32x4 acc[4][4];
#pragma unroll
    for (int m = 0; m < 4; ++m)
#pragma unroll
        for (int n = 0; n < 4; ++n)
            acc[m][n] = f32x4{0.f, 0.f, 0.f, 0.f};

    for (int k0 = 0; k0 < K; k0 += 64) {
#pragma unroll
        for (int p = 0; p < 4; ++p) {
            const int c   = p * 4 + w;          // chunk 0..15 (uniform per wave)
            const int row = c * 8 + lr;
            const ushort* gA = A + (size_t)(bRow + row) * lda + (k0 + scol);
            const ushort* gB = B + (size_t)(bCol + row) * ldb + (k0 + scol);
            __builtin_amdgcn_global_load_lds((const g_void_t*)gA,
                (lds_void_t*)((char*)sA + c * 1024), 16, 0, 0);
            __builtin_amdgcn_global_load_lds((const g_void_t*)gB,
                (lds_void_t*)((char*)sB + c * 1024), 16, 0, 0);
        }
        __syncthreads();

        bf16x8 af[4][2], bfv[4][2];
#pragma unroll
        for (int m = 0; m < 4; ++m) {
            const int ar = wr * 64 + m * 16 + (l & 15);
#pragma unroll
            for (int ks = 0; ks < 2; ++ks) {
                const int slot = (ks * 4 + (l >> 4)) ^ (ar & 7);
                af[m][ks] = *reinterpret_cast<const bf16x8*>(
                    (const char*)sA + ar * 128 + slot * 16);
            }
        }
#pragma unroll
        for (int n = 0; n < 4; ++n) {
            const int br = wc * 64 + n * 16 + (l & 15);
#pragma unroll
            for (int ks = 0; ks < 2; ++ks) {
                const int slot = (ks * 4 + (l >> 4)) ^ (br & 7);
                bfv[n][ks] = *reinterpret_cast<const bf16x8*>(
                    (const char*)sB + br * 128 + slot * 16);
            }
        }
#pragma unroll
        for (int ks = 0; ks < 2; ++ks)
#pragma unroll
            for (int m = 0; m < 4; ++m)
#pragma unroll
                for (int n = 0; n < 4; ++n)
                    acc[m][n] = __builtin_amdgcn_mfma_f32_16x16x32_bf16(
                        af[m][ks], bfv[n][ks], acc[m][n], 0, 0, 0);
        __syncthreads();
    }

    // epilogue: C/D layout col = lane&15, row = (lane>>4)*4 + r  (m89-verified)
    const int cl = l & 15;
#pragma unroll
    for (int n = 0; n < 4; ++n) {
        const int col = bCol + wc * 64 + n * 16 + cl;
        const float bv = HAS_BIAS ? bias[col] : 0.f;
#pragma unroll
        for (int m = 0; m < 4; ++m) {
#pragma unroll
            for (int r = 0; r < 4; ++r) {
                const int row = bRow + wr * 64 + m * 16 + (l >> 4) * 4 + r;
                const float v = (acc[m][n][r] + bv) * alpha;
                if constexpr (sizeof(CT) == 2)
                    ((ushort*)C)[(size_t)row * ldc + col] = f2b(v);
                else
                    ((float*)C)[(size_t)row * ldc + col] = v;
            }
        }
    }
}

// ---------------- in-place row softmax on bf16 [rows][2048] ----------------
__global__ __launch_bounds__(256) void softmax_rows(ushort* __restrict__ S)
{
    __shared__ float red[8];
    const size_t row = blockIdx.x;
    ushort* p = S + row * 2048;
    const int tid = threadIdx.x;

    uint4 v = reinterpret_cast<uint4*>(p)[tid];   // 8 bf16
    float f[8];
    const unsigned int* wv = reinterpret_cast<const unsigned int*>(&v);
#pragma unroll
    for (int j = 0; j < 4; ++j) {
        f[2 * j]     = b2f(wv[j] & 0xFFFFu);
        f[2 * j + 1] = b2f(wv[j] >> 16);
    }
    float mx = f[0];
#pragma unroll
    for (int j = 1; j < 8; ++j) mx = fmaxf(mx, f[j]);
#pragma unroll
    for (int s = 1; s < 64; s <<= 1) mx = fmaxf(mx, __shfl_xor(mx, s));
    if ((tid & 63) == 0) red[tid >> 6] = mx;
    __syncthreads();
    mx = fmaxf(fmaxf(red[0], red[1]), fmaxf(red[2], red[3]));

    float sum = 0.f;
#pragma unroll
    for (int j = 0; j < 8; ++j) { f[j] = __expf(f[j] - mx); sum += f[j]; }
#pragma unroll
    for (int s = 1; s < 64; s <<= 1) sum += __shfl_xor(sum, s);
    if ((tid & 63) == 0) red[4 + (tid >> 6)] = sum;
    __syncthreads();
    sum = (red[4] + red[5]) + (red[6] + red[7]);
    const float inv = 1.0f / sum;

    uint4 o;
    unsigned int* wo = reinterpret_cast<unsigned int*>(&o);
#pragma unroll
    for (int j = 0; j < 4; ++j) {
        const unsigned int lo = f2b(f[2 * j] * inv);
        const unsigned int hi = f2b(f[2 * j + 1] * inv);
        wo[j] = lo | (hi << 16);
    }
    reinterpret_cast<uint4*>(p)[tid] = o;
}

// ---------------- tiled bf16 transpose: V[b][s][e] -> Vt[b][e][s] ----------
__global__ __launch_bounds__(256) void transpose_v(
    const ushort* __restrict__ V, ushort* __restrict__ Vt)
{
    __shared__ ushort t[64][65];
    const int b  = blockIdx.z;
    const int e0 = blockIdx.x * 64;
    const int s0 = blockIdx.y * 64;
    const int tid = threadIdx.x;
    const int cg = (tid & 15) * 4;
    const int r0 = tid >> 4;

    const ushort* Vb = V + (size_t)b * 2048 * 1024;
#pragma unroll
    for (int p = 0; p < 4; ++p) {
        const int r = r0 + p * 16;
        ushort4 x = *reinterpret_cast<const ushort4*>(
            Vb + (size_t)(s0 + r) * 1024 + e0 + cg);
        t[r][cg + 0] = x.x; t[r][cg + 1] = x.y;
        t[r][cg + 2] = x.z; t[r][cg + 3] = x.w;
    }
    __syncthreads();
    ushort* Vtb = Vt + (size_t)b * 1024 * 2048;
#pragma unroll
    for (int p = 0; p < 4; ++p) {
        const int e = r0 + p * 16;
        ushort4 o;
        o.x = t[cg + 0][e]; o.y = t[cg + 1][e];
        o.z = t[cg + 2][e]; o.w = t[cg + 3][e];
        *reinterpret_cast<ushort4*>(Vtb + (size_t)(e0 + e) * 2048 + s0 + cg) = o;
    }
}

// ---------------- launch ----------------
extern "C" void kernel_launch(void* const* d_in, const int* in_sizes, int n_in,
                              void* d_out, int out_size, void* d_ws, size_t ws_size,
                              hipStream_t stream)
{
    const float* x  = (const float*)d_in[0];
    const float* Wq = (const float*)d_in[1];
    const float* bq = (const float*)d_in[2];
    const float* Wk = (const float*)d_in[3];
    const float* bk = (const float*)d_in[4];
    const float* Wv = (const float*)d_in[5];
    const float* bv = (const float*)d_in[6];
    const float* Wo = (const float*)d_in[7];
    const float* bo = (const float*)d_in[8];

    char* ws = (char*)d_ws;
    ushort* xb  = (ushort*)(ws);                 // 16 MB  [8192][1024]
    ushort* Wqb = (ushort*)(ws + 16777216);      // 2 MB
    ushort* Wkb = (ushort*)(ws + 18874368);
    ushort* Wvb = (ushort*)(ws + 20971520);
    ushort* Wob = (ushort*)(ws + 23068672);
    ushort* Qb  = (ushort*)(ws + 25165824);      // 16 MB (pre-scaled by 1/32)
    ushort* Kb  = (ushort*)(ws + 41943040);      // 16 MB
    ushort* Vb  = (ushort*)(ws + 58720256);      // 16 MB
    ushort* Vtb = (ushort*)(ws + 75497472);      // 16 MB [4][1024][2048]
    ushort* Sb  = (ushort*)(ws + 92274688);      // 32 MB [4][2048][2048] scores->probs
    ushort* Ob  = (ushort*)(ws + 125829120);     // 16 MB [8192][1024]

    // casts
    cast_f32_bf16<<<2048, 256, 0, stream>>>(x,  xb,  2097152);
    cast_f32_bf16<<<1024, 256, 0, stream>>>(Wq, Wqb, 262144);
    cast_f32_bf16<<<1024, 256, 0, stream>>>(Wk, Wkb, 262144);
    cast_f32_bf16<<<1024, 256, 0, stream>>>(Wv, Wvb, 262144);
    cast_f32_bf16<<<1024, 256, 0, stream>>>(Wo, Wob, 262144);

    // Q/K/V projections: [8192,1024] = xb @ W^T + b ; Q pre-scaled by 1/sqrt(E)
    gemm_bt<ushort, true><<<dim3(8, 64, 1), 256, 0, stream>>>(
        xb, Wqb, bq, Qb, 1024, 1024, 1024, 1024, 0, 0, 0, 0.03125f);
    gemm_bt<ushort, true><<<dim3(8, 64, 1), 256, 0, stream>>>(
        xb, Wkb, bk, Kb, 1024, 1024, 1024, 1024, 0, 0, 0, 1.0f);
    gemm_bt<ushort, true><<<dim3(8, 64, 1), 256, 0, stream>>>(
        xb, Wvb, bv, Vb, 1024, 1024, 1024, 1024, 0, 0, 0, 1.0f);

    // V^T for the PV GEMM
    transpose_v<<<dim3(16, 32, 4), 256, 0, stream>>>(Vb, Vtb);

    // scores: per batch [2048,2048] = Qb @ Kb^T  (bf16 out)
    gemm_bt<ushort, false><<<dim3(16, 16, 4), 256, 0, stream>>>(
        Qb, Kb, nullptr, Sb, 1024, 1024, 2048, 1024,
        2048L * 1024, 2048L * 1024, 2048L * 2048, 1.0f);

    // softmax rows, in place
    softmax_rows<<<8192, 256, 0, stream>>>(Sb);

    // O = P @ V : per batch [2048,1024] = Sb @ Vt^T
    gemm_bt<ushort, false><<<dim3(8, 16, 4), 256, 0, stream>>>(
        Sb, Vtb, nullptr, Ob, 2048, 2048, 1024, 2048,
        2048L * 2048, 1024L * 2048, 2048L * 1024, 1.0f);

    // out = O @ Wo^T + bo (fp32)
    gemm_bt<float, true><<<dim3(8, 64, 1), 256, 0, stream>>>(
        Ob, Wob, bo, (float*)d_out, 1024, 1024, 1024, 1024, 0, 0, 0, 1.0f);
}

// Round 3
// 303.473 us; speedup vs baseline: 1.0386x; 1.0386x over previous
//
#include <hip/hip_runtime.h>
#include <hip/hip_bf16.h>
#include <stdint.h>

typedef short bf16x8 __attribute__((ext_vector_type(8)));
typedef float f32x4 __attribute__((ext_vector_type(4)));
typedef __attribute__((address_space(3))) void lds_void_t;
typedef __attribute__((address_space(1))) void g_void_t;

static __device__ __forceinline__ unsigned short f2b(float f) {
    __hip_bfloat16 b = __float2bfloat16(f);
    return __builtin_bit_cast(unsigned short, b);
}
static __device__ __forceinline__ float b2f(unsigned int u) {
    return __builtin_bit_cast(float, u << 16);
}

// ---------------- cast fp32 -> bf16, vectorized ----------------
__global__ __launch_bounds__(256) void cast_f32_bf16(
    const float* __restrict__ in, ushort* __restrict__ out, int n4)
{
    int i = blockIdx.x * blockDim.x + threadIdx.x;
    const int stride = gridDim.x * blockDim.x;
    for (; i < n4; i += stride) {
        float4 v = reinterpret_cast<const float4*>(in)[i];
        ushort4 o;
        o.x = f2b(v.x); o.y = f2b(v.y); o.z = f2b(v.z); o.w = f2b(v.w);
        reinterpret_cast<ushort4*>(out)[i] = o;
    }
}

// ---------------- concat 3 fp32 bias vectors [1024] -> [3072] -------------
__global__ __launch_bounds__(256) void concat_bias(
    const float* __restrict__ b0, const float* __restrict__ b1,
    const float* __restrict__ b2, float* __restrict__ out)
{
    const int i = blockIdx.x * blockDim.x + threadIdx.x;  // 0..3071
    const int sec = i >> 10, off = i & 1023;
    out[i] = sec == 0 ? b0[off] : (sec == 1 ? b1[off] : b2[off]);
}

// ---------------- 128x128 bf16 GEMM, C = (A * B^T + bias) * alpha ---------
// A: [M][lda] bf16 (K contiguous), B: [N][ldb] bf16 (K contiguous)
// grid: (N/128, M/128, batch); block 256 (4 waves, 2x2 wave grid)
// XCD-aware bijective swizzle (T1, m204 formula; grids here all have nwg%8==0)
template<typename CT, bool HAS_BIAS>
__global__ __launch_bounds__(256, 4)
void gemm_bt(const ushort* __restrict__ A, const ushort* __restrict__ B,
             const float* __restrict__ bias, CT* __restrict__ C,
             int lda, int ldb, int ldc, int K,
             long strideA, long strideB, long strideC, float alpha)
{
    __shared__ __align__(16) ushort sA[128 * 64];
    __shared__ __align__(16) ushort sB[128 * 64];

    const int bz = blockIdx.z;
    A += (size_t)bz * strideA;
    B += (size_t)bz * strideB;
    C += (size_t)bz * strideC;

    // XCD swizzle: XCD k (flat%8==k) gets contiguous logical chunk -> row-major
    // row-chunks share A panels within one XCD's L2.
    const int gx = gridDim.x, gy = gridDim.y;
    const int nwg = gx * gy;
    int bx = blockIdx.x, by = blockIdx.y;
    if ((nwg & 7) == 0) {
        const int flat = blockIdx.x + gx * blockIdx.y;
        const int cpx = nwg >> 3;
        const int u = (flat & 7) * cpx + (flat >> 3);
        bx = u % gx;
        by = u / gx;
    }

    const int tid = threadIdx.x;
    const int w   = tid >> 6;
    const int l   = tid & 63;
    const int wr  = w >> 1;
    const int wc  = w & 1;

    const int bRow = by * 128;
    const int bCol = bx * 128;

    // staging: each wave covers 8 chunks (4 for A, 4 for B), chunk = 1KB = 8 rows.
    // LDS holds the XOR-swizzled layout: LDS[row][slot16] = global[row][slot16 ^ (row&7)].
    // Achieved by pre-swizzling the per-lane GLOBAL source (linear LDS dest).
    const int lr   = l >> 3;                    // row within 8-row chunk
    const int scol = (((l & 7) ^ lr) << 3);     // swizzled source col (elems)

    f32x4 acc[4][4];
#pragma unroll
    for (int m = 0; m < 4; ++m)
#pragma unroll
        for (int n = 0; n < 4; ++n)
            acc[m][n] = f32x4{0.f, 0.f, 0.f, 0.f};

    for (int k0 = 0; k0 < K; k0 += 64) {
#pragma unroll
        for (int p = 0; p < 4; ++p) {
            const int c   = p * 4 + w;          // chunk 0..15 (uniform per wave)
            const int row = c * 8 + lr;
            const ushort* gA = A + (size_t)(bRow + row) * lda + (k0 + scol);
            const ushort* gB = B + (size_t)(bCol + row) * ldb + (k0 + scol);
            __builtin_amdgcn_global_load_lds((const g_void_t*)gA,
                (lds_void_t*)((char*)sA + c * 1024), 16, 0, 0);
            __builtin_amdgcn_global_load_lds((const g_void_t*)gB,
                (lds_void_t*)((char*)sB + c * 1024), 16, 0, 0);
        }
        __syncthreads();

        bf16x8 af[4][2], bfv[4][2];
#pragma unroll
        for (int m = 0; m < 4; ++m) {
            const int ar = wr * 64 + m * 16 + (l & 15);
#pragma unroll
            for (int ks = 0; ks < 2; ++ks) {
                const int slot = (ks * 4 + (l >> 4)) ^ (ar & 7);
                af[m][ks] = *reinterpret_cast<const bf16x8*>(
                    (const char*)sA + ar * 128 + slot * 16);
            }
        }
#pragma unroll
        for (int n = 0; n < 4; ++n) {
            const int br = wc * 64 + n * 16 + (l & 15);
#pragma unroll
            for (int ks = 0; ks < 2; ++ks) {
                const int slot = (ks * 4 + (l >> 4)) ^ (br & 7);
                bfv[n][ks] = *reinterpret_cast<const bf16x8*>(
                    (const char*)sB + br * 128 + slot * 16);
            }
        }
#pragma unroll
        for (int ks = 0; ks < 2; ++ks)
#pragma unroll
            for (int m = 0; m < 4; ++m)
#pragma unroll
                for (int n = 0; n < 4; ++n)
                    acc[m][n] = __builtin_amdgcn_mfma_f32_16x16x32_bf16(
                        af[m][ks], bfv[n][ks], acc[m][n], 0, 0, 0);
        __syncthreads();
    }

    // epilogue: C/D layout col = lane&15, row = (lane>>4)*4 + r  (m89-verified)
    const int cl = l & 15;
#pragma unroll
    for (int n = 0; n < 4; ++n) {
        const int col = bCol + wc * 64 + n * 16 + cl;
        const float bv = HAS_BIAS ? bias[col] : 0.f;
#pragma unroll
        for (int m = 0; m < 4; ++m) {
#pragma unroll
            for (int r = 0; r < 4; ++r) {
                const int row = bRow + wr * 64 + m * 16 + (l >> 4) * 4 + r;
                const float v = (acc[m][n][r] + bv) * alpha;
                if constexpr (sizeof(CT) == 2)
                    ((ushort*)C)[(size_t)row * ldc + col] = f2b(v);
                else
                    ((float*)C)[(size_t)row * ldc + col] = v;
            }
        }
    }
}

// ---------------- in-place row softmax on bf16 [rows][2048] ----------------
__global__ __launch_bounds__(256) void softmax_rows(ushort* __restrict__ S)
{
    __shared__ float red[8];
    const size_t row = blockIdx.x;
    ushort* p = S + row * 2048;
    const int tid = threadIdx.x;

    uint4 v = reinterpret_cast<uint4*>(p)[tid];   // 8 bf16
    float f[8];
    const unsigned int* wv = reinterpret_cast<const unsigned int*>(&v);
#pragma unroll
    for (int j = 0; j < 4; ++j) {
        f[2 * j]     = b2f(wv[j] & 0xFFFFu);
        f[2 * j + 1] = b2f(wv[j] >> 16);
    }
    float mx = f[0];
#pragma unroll
    for (int j = 1; j < 8; ++j) mx = fmaxf(mx, f[j]);
#pragma unroll
    for (int s = 1; s < 64; s <<= 1) mx = fmaxf(mx, __shfl_xor(mx, s));
    if ((tid & 63) == 0) red[tid >> 6] = mx;
    __syncthreads();
    mx = fmaxf(fmaxf(red[0], red[1]), fmaxf(red[2], red[3]));

    float sum = 0.f;
#pragma unroll
    for (int j = 0; j < 8; ++j) { f[j] = __expf(f[j] - mx); sum += f[j]; }
#pragma unroll
    for (int s = 1; s < 64; s <<= 1) sum += __shfl_xor(sum, s);
    if ((tid & 63) == 0) red[4 + (tid >> 6)] = sum;
    __syncthreads();
    sum = (red[4] + red[5]) + (red[6] + red[7]);
    const float inv = 1.0f / sum;

    uint4 o;
    unsigned int* wo = reinterpret_cast<unsigned int*>(&o);
#pragma unroll
    for (int j = 0; j < 4; ++j) {
        const unsigned int lo = f2b(f[2 * j] * inv);
        const unsigned int hi = f2b(f[2 * j + 1] * inv);
        wo[j] = lo | (hi << 16);
    }
    reinterpret_cast<uint4*>(p)[tid] = o;
}

// ---------------- tiled bf16 transpose: V[b][s][ld] -> Vt[b][e][s] ----------
__global__ __launch_bounds__(256) void transpose_v(
    const ushort* __restrict__ V, ushort* __restrict__ Vt, int ldv, long strideV)
{
    __shared__ ushort t[64][65];
    const int b  = blockIdx.z;
    const int e0 = blockIdx.x * 64;
    const int s0 = blockIdx.y * 64;
    const int tid = threadIdx.x;
    const int cg = (tid & 15) * 4;
    const int r0 = tid >> 4;

    const ushort* Vb = V + (size_t)b * strideV;
#pragma unroll
    for (int p = 0; p < 4; ++p) {
        const int r = r0 + p * 16;
        ushort4 x = *reinterpret_cast<const ushort4*>(
            Vb + (size_t)(s0 + r) * ldv + e0 + cg);
        t[r][cg + 0] = x.x; t[r][cg + 1] = x.y;
        t[r][cg + 2] = x.z; t[r][cg + 3] = x.w;
    }
    __syncthreads();
    ushort* Vtb = Vt + (size_t)b * 1024 * 2048;
#pragma unroll
    for (int p = 0; p < 4; ++p) {
        const int e = r0 + p * 16;
        ushort4 o;
        o.x = t[cg + 0][e]; o.y = t[cg + 1][e];
        o.z = t[cg + 2][e]; o.w = t[cg + 3][e];
        *reinterpret_cast<ushort4*>(Vtb + (size_t)(e0 + e) * 2048 + s0 + cg) = o;
    }
}

// ---------------- launch ----------------
extern "C" void kernel_launch(void* const* d_in, const int* in_sizes, int n_in,
                              void* d_out, int out_size, void* d_ws, size_t ws_size,
                              hipStream_t stream)
{
    const float* x  = (const float*)d_in[0];
    const float* Wq = (const float*)d_in[1];
    const float* bq = (const float*)d_in[2];
    const float* Wk = (const float*)d_in[3];
    const float* bk = (const float*)d_in[4];
    const float* Wv = (const float*)d_in[5];
    const float* bv = (const float*)d_in[6];
    const float* Wo = (const float*)d_in[7];
    const float* bo = (const float*)d_in[8];

    char* ws = (char*)d_ws;
    ushort* xb    = (ushort*)(ws);                 // 16 MB  [8192][1024]
    ushort* Wqkvb = (ushort*)(ws + 16777216);      // 6 MB   [3072][1024] (Wq;Wk;Wv)
    ushort* Wob   = (ushort*)(ws + 23068672);      // 2 MB
    float*  bqkv  = (float*) (ws + 25165824);      // 12 KB  [3072]
    ushort* QKVb  = (ushort*)(ws + 26214400);      // 48 MB  [8192][3072]
    ushort* Vtb   = (ushort*)(ws + 76546048);      // 16 MB  [4][1024][2048]
    ushort* Sb    = (ushort*)(ws + 93323264);      // 32 MB  [4][2048][2048]
    ushort* Ob    = (ushort*)(ws + 126877696);     // 16 MB  [8192][1024]

    // casts
    cast_f32_bf16<<<2048, 256, 0, stream>>>(x,  xb, 2097152);
    cast_f32_bf16<<<1024, 256, 0, stream>>>(Wq, Wqkvb,           262144);
    cast_f32_bf16<<<1024, 256, 0, stream>>>(Wk, Wqkvb + 1048576, 262144);
    cast_f32_bf16<<<1024, 256, 0, stream>>>(Wv, Wqkvb + 2097152, 262144);
    cast_f32_bf16<<<1024, 256, 0, stream>>>(Wo, Wob, 262144);
    concat_bias<<<12, 256, 0, stream>>>(bq, bk, bv, bqkv);

    // fused QKV projection: [8192,3072] = xb @ Wqkv^T + bqkv (unscaled)
    gemm_bt<ushort, true><<<dim3(24, 64, 1), 256, 0, stream>>>(
        xb, Wqkvb, bqkv, QKVb, 1024, 1024, 3072, 1024, 0, 0, 0, 1.0f);

    // V^T for the PV GEMM (V = QKVb columns [2048,3072))
    transpose_v<<<dim3(16, 32, 4), 256, 0, stream>>>(
        QKVb + 2048, Vtb, 3072, 2048L * 3072);

    // scores: per batch [2048,2048] = (Q @ K^T) / 32  (bf16 out)
    gemm_bt<ushort, false><<<dim3(16, 16, 4), 256, 0, stream>>>(
        QKVb, QKVb + 1024, nullptr, Sb, 3072, 3072, 2048, 1024,
        2048L * 3072, 2048L * 3072, 2048L * 2048, 0.03125f);

    // softmax rows, in place
    softmax_rows<<<8192, 256, 0, stream>>>(Sb);

    // O = P @ V : per batch [2048,1024] = Sb @ Vt^T
    gemm_bt<ushort, false><<<dim3(8, 16, 4), 256, 0, stream>>>(
        Sb, Vtb, nullptr, Ob, 2048, 2048, 1024, 2048,
        2048L * 2048, 1024L * 2048, 2048L * 1024, 1.0f);

    // out = O @ Wo^T + bo (fp32)
    gemm_bt<float, true><<<dim3(8, 64, 1), 256, 0, stream>>>(
        Ob, Wob, bo, (float*)d_out, 1024, 1024, 1024, 1024, 0, 0, 0, 1.0f);
}

// Round 4
// 293.569 us; speedup vs baseline: 1.0736x; 1.0337x over previous
//
#include <hip/hip_runtime.h>
#include <hip/hip_bf16.h>
#include <stdint.h>

typedef short bf16x8 __attribute__((ext_vector_type(8)));
typedef float f32x4 __attribute__((ext_vector_type(4)));
typedef __attribute__((address_space(3))) void lds_void_t;
typedef __attribute__((address_space(1))) void g_void_t;

static __device__ __forceinline__ unsigned short f2b(float f) {
    __hip_bfloat16 b = __float2bfloat16(f);
    return __builtin_bit_cast(unsigned short, b);
}
static __device__ __forceinline__ float b2f(unsigned int u) {
    return __builtin_bit_cast(float, u << 16);
}

// ---------------- fused prep: cast x + 4 weights to bf16, concat biases ----
// weights land contiguously at wqkvb: [Wq;Wk;Wv;Wo], each 1024x1024
__global__ __launch_bounds__(256) void prep(
    const float* __restrict__ x,
    const float* __restrict__ wq, const float* __restrict__ wk,
    const float* __restrict__ wv, const float* __restrict__ wo,
    const float* __restrict__ bq, const float* __restrict__ bk,
    const float* __restrict__ bv_, float* __restrict__ bqkv,
    ushort* __restrict__ xb, ushort* __restrict__ wqkvb)
{
    const int T = 3145728;  // float4 units: x 2097152 + 4 * 262144
    int i = blockIdx.x * 256 + threadIdx.x;
    const int stride = gridDim.x * 256;
    for (; i < T; i += stride) {
        const float* src; ushort* dst; int off;
        if (i < 2097152) { src = x; dst = xb; off = i; }
        else {
            const int j = i - 2097152;
            const int w = j >> 18;
            off = j & 262143;
            src = (w == 0) ? wq : (w == 1) ? wk : (w == 2) ? wv : wo;
            dst = wqkvb + (w << 20);   // w * 1048576 ushorts
        }
        float4 v = reinterpret_cast<const float4*>(src)[off];
        ushort4 o;
        o.x = f2b(v.x); o.y = f2b(v.y); o.z = f2b(v.z); o.w = f2b(v.w);
        reinterpret_cast<ushort4*>(dst)[off] = o;
    }
    const int t = blockIdx.x * 256 + threadIdx.x;
    if (t < 3072) {
        const int sec = t >> 10, of = t & 1023;
        bqkv[t] = sec == 0 ? bq[of] : (sec == 1 ? bk[of] : bv_[of]);
    }
}

// ---------------- 128x128 bf16 GEMM, C = (A * B^T + bias) * alpha ---------
// A: [M][lda] bf16 (K contiguous), B: [N][ldb] bf16 (K contiguous)
// grid: (N/128, M/128, batch); block 256 (4 waves, 2x2 wave grid)
// XCD-aware bijective swizzle (T1); bf16 output goes through an LDS bounce
// so global stores are 16B full-sector dwordx4.
template<typename CT, bool HAS_BIAS>
__global__ __launch_bounds__(256, 4)
void gemm_bt(const ushort* __restrict__ A, const ushort* __restrict__ B,
             const float* __restrict__ bias, CT* __restrict__ C,
             int lda, int ldb, int ldc, int K,
             long strideA, long strideB, long strideC, float alpha)
{
    __shared__ __align__(16) ushort smem[128 * 64 * 2];   // 32 KB
    ushort* sA = smem;
    ushort* sB = smem + 128 * 64;

    const int bz = blockIdx.z;
    A += (size_t)bz * strideA;
    B += (size_t)bz * strideB;
    C += (size_t)bz * strideC;

    // XCD swizzle: XCD k (flat%8==k) gets a contiguous row-chunk of the grid.
    const int gx = gridDim.x, gy = gridDim.y;
    const int nwg = gx * gy;
    int bx = blockIdx.x, by = blockIdx.y;
    if ((nwg & 7) == 0) {
        const int flat = blockIdx.x + gx * blockIdx.y;
        const int cpx = nwg >> 3;
        const int u = (flat & 7) * cpx + (flat >> 3);
        bx = u % gx;
        by = u / gx;
    }

    const int tid = threadIdx.x;
    const int w   = tid >> 6;
    const int l   = tid & 63;
    const int wr  = w >> 1;
    const int wc  = w & 1;

    const int bRow = by * 128;
    const int bCol = bx * 128;

    // staging: chunk = 1KB = 8 rows; LDS[row][slot16] = global[row][slot16 ^ (row&7)]
    // via pre-swizzled GLOBAL source (linear LDS dest).
    const int lr   = l >> 3;
    const int scol = (((l & 7) ^ lr) << 3);

    f32x4 acc[4][4];
#pragma unroll
    for (int m = 0; m < 4; ++m)
#pragma unroll
        for (int n = 0; n < 4; ++n)
            acc[m][n] = f32x4{0.f, 0.f, 0.f, 0.f};

    for (int k0 = 0; k0 < K; k0 += 64) {
#pragma unroll
        for (int p = 0; p < 4; ++p) {
            const int c   = p * 4 + w;
            const int row = c * 8 + lr;
            const ushort* gA = A + (size_t)(bRow + row) * lda + (k0 + scol);
            const ushort* gB = B + (size_t)(bCol + row) * ldb + (k0 + scol);
            __builtin_amdgcn_global_load_lds((const g_void_t*)gA,
                (lds_void_t*)((char*)sA + c * 1024), 16, 0, 0);
            __builtin_amdgcn_global_load_lds((const g_void_t*)gB,
                (lds_void_t*)((char*)sB + c * 1024), 16, 0, 0);
        }
        __syncthreads();

        bf16x8 af[4][2], bfv[4][2];
#pragma unroll
        for (int m = 0; m < 4; ++m) {
            const int ar = wr * 64 + m * 16 + (l & 15);
#pragma unroll
            for (int ks = 0; ks < 2; ++ks) {
                const int slot = (ks * 4 + (l >> 4)) ^ (ar & 7);
                af[m][ks] = *reinterpret_cast<const bf16x8*>(
                    (const char*)sA + ar * 128 + slot * 16);
            }
        }
#pragma unroll
        for (int n = 0; n < 4; ++n) {
            const int br = wc * 64 + n * 16 + (l & 15);
#pragma unroll
            for (int ks = 0; ks < 2; ++ks) {
                const int slot = (ks * 4 + (l >> 4)) ^ (br & 7);
                bfv[n][ks] = *reinterpret_cast<const bf16x8*>(
                    (const char*)sB + br * 128 + slot * 16);
            }
        }
#pragma unroll
        for (int ks = 0; ks < 2; ++ks)
#pragma unroll
            for (int m = 0; m < 4; ++m)
#pragma unroll
                for (int n = 0; n < 4; ++n)
                    acc[m][n] = __builtin_amdgcn_mfma_f32_16x16x32_bf16(
                        af[m][ks], bfv[n][ks], acc[m][n], 0, 0, 0);
        __syncthreads();
    }

    // epilogue. C/D layout: col = lane&15, row = (lane>>4)*4 + r (m89-verified)
    const int cl = l & 15;
    if constexpr (sizeof(CT) == 2) {
        // bf16: bounce through LDS (32 KB tile fits exactly in smem), then
        // 16B coalesced stores (full 64B sectors per 4 lanes).
        ushort* st = smem;   // [128][128] bf16
#pragma unroll
        for (int n = 0; n < 4; ++n) {
            const int col = wc * 64 + n * 16 + cl;
            const float bv = HAS_BIAS ? bias[bCol + col] : 0.f;
#pragma unroll
            for (int m = 0; m < 4; ++m) {
                const int row0 = wr * 64 + m * 16 + (l >> 4) * 4;
#pragma unroll
                for (int r = 0; r < 4; ++r)
                    st[(row0 + r) * 128 + col] = f2b((acc[m][n][r] + bv) * alpha);
            }
        }
        __syncthreads();
        // 2048 chunks of 16B (8 per thread); 16 threads cover one 256B row
#pragma unroll
        for (int i = 0; i < 8; ++i) {
            const int c    = tid + i * 256;
            const int row  = c >> 4;
            const int col8 = (c & 15) * 8;
            *reinterpret_cast<uint4*>(
                (ushort*)C + (size_t)(bRow + row) * ldc + bCol + col8) =
                *reinterpret_cast<const uint4*>(st + row * 128 + col8);
        }
    } else {
        // fp32: scalar stores are already full-sector (16 lanes x 4B = 64B)
#pragma unroll
        for (int n = 0; n < 4; ++n) {
            const int col = bCol + wc * 64 + n * 16 + cl;
            const float bv = HAS_BIAS ? bias[col] : 0.f;
#pragma unroll
            for (int m = 0; m < 4; ++m) {
#pragma unroll
                for (int r = 0; r < 4; ++r) {
                    const int row = bRow + wr * 64 + m * 16 + (l >> 4) * 4 + r;
                    ((float*)C)[(size_t)row * ldc + col] = (acc[m][n][r] + bv) * alpha;
                }
            }
        }
    }
}

// ---------------- in-place row softmax on bf16 [rows][2048] ----------------
__global__ __launch_bounds__(256) void softmax_rows(ushort* __restrict__ S)
{
    __shared__ float red[8];
    const size_t row = blockIdx.x;
    ushort* p = S + row * 2048;
    const int tid = threadIdx.x;

    uint4 v = reinterpret_cast<uint4*>(p)[tid];   // 8 bf16
    float f[8];
    const unsigned int* wv = reinterpret_cast<const unsigned int*>(&v);
#pragma unroll
    for (int j = 0; j < 4; ++j) {
        f[2 * j]     = b2f(wv[j] & 0xFFFFu);
        f[2 * j + 1] = b2f(wv[j] >> 16);
    }
    float mx = f[0];
#pragma unroll
    for (int j = 1; j < 8; ++j) mx = fmaxf(mx, f[j]);
#pragma unroll
    for (int s = 1; s < 64; s <<= 1) mx = fmaxf(mx, __shfl_xor(mx, s));
    if ((tid & 63) == 0) red[tid >> 6] = mx;
    __syncthreads();
    mx = fmaxf(fmaxf(red[0], red[1]), fmaxf(red[2], red[3]));

    float sum = 0.f;
#pragma unroll
    for (int j = 0; j < 8; ++j) { f[j] = __expf(f[j] - mx); sum += f[j]; }
#pragma unroll
    for (int s = 1; s < 64; s <<= 1) sum += __shfl_xor(sum, s);
    if ((tid & 63) == 0) red[4 + (tid >> 6)] = sum;
    __syncthreads();
    sum = (red[4] + red[5]) + (red[6] + red[7]);
    const float inv = 1.0f / sum;

    uint4 o;
    unsigned int* wo = reinterpret_cast<unsigned int*>(&o);
#pragma unroll
    for (int j = 0; j < 4; ++j) {
        const unsigned int lo = f2b(f[2 * j] * inv);
        const unsigned int hi = f2b(f[2 * j + 1] * inv);
        wo[j] = lo | (hi << 16);
    }
    reinterpret_cast<uint4*>(p)[tid] = o;
}

// ---------------- tiled bf16 transpose: V[b][s][ld] -> Vt[b][e][s] ----------
__global__ __launch_bounds__(256) void transpose_v(
    const ushort* __restrict__ V, ushort* __restrict__ Vt, int ldv, long strideV)
{
    __shared__ ushort t[64][65];
    const int b  = blockIdx.z;
    const int e0 = blockIdx.x * 64;
    const int s0 = blockIdx.y * 64;
    const int tid = threadIdx.x;
    const int cg = (tid & 15) * 4;
    const int r0 = tid >> 4;

    const ushort* Vb = V + (size_t)b * strideV;
#pragma unroll
    for (int p = 0; p < 4; ++p) {
        const int r = r0 + p * 16;
        ushort4 x = *reinterpret_cast<const ushort4*>(
            Vb + (size_t)(s0 + r) * ldv + e0 + cg);
        t[r][cg + 0] = x.x; t[r][cg + 1] = x.y;
        t[r][cg + 2] = x.z; t[r][cg + 3] = x.w;
    }
    __syncthreads();
    ushort* Vtb = Vt + (size_t)b * 1024 * 2048;
#pragma unroll
    for (int p = 0; p < 4; ++p) {
        const int e = r0 + p * 16;
        ushort4 o;
        o.x = t[cg + 0][e]; o.y = t[cg + 1][e];
        o.z = t[cg + 2][e]; o.w = t[cg + 3][e];
        *reinterpret_cast<ushort4*>(Vtb + (size_t)(e0 + e) * 2048 + s0 + cg) = o;
    }
}

// ---------------- launch ----------------
extern "C" void kernel_launch(void* const* d_in, const int* in_sizes, int n_in,
                              void* d_out, int out_size, void* d_ws, size_t ws_size,
                              hipStream_t stream)
{
    const float* x  = (const float*)d_in[0];
    const float* Wq = (const float*)d_in[1];
    const float* bq = (const float*)d_in[2];
    const float* Wk = (const float*)d_in[3];
    const float* bk = (const float*)d_in[4];
    const float* Wv = (const float*)d_in[5];
    const float* bv = (const float*)d_in[6];
    const float* Wo = (const float*)d_in[7];
    const float* bo = (const float*)d_in[8];

    char* ws = (char*)d_ws;
    ushort* xb    = (ushort*)(ws);                 // 16 MB  [8192][1024]
    ushort* Wqkvb = (ushort*)(ws + 16777216);      // 8 MB   [Wq;Wk;Wv;Wo] each 1024x1024
    ushort* Wob   = Wqkvb + 3 * 1048576;
    float*  bqkv  = (float*) (ws + 25165824);      // 12 KB  [3072]
    ushort* QKVb  = (ushort*)(ws + 26214400);      // 48 MB  [8192][3072]
    ushort* Vtb   = (ushort*)(ws + 76546048);      // 16 MB  [4][1024][2048]
    ushort* Sb    = (ushort*)(ws + 93323264);      // 32 MB  [4][2048][2048]
    ushort* Ob    = (ushort*)(ws + 126877696);     // 16 MB  [8192][1024]

    // fused casts + bias concat
    prep<<<2048, 256, 0, stream>>>(x, Wq, Wk, Wv, Wo, bq, bk, bv, bqkv, xb, Wqkvb);

    // fused QKV projection: [8192,3072] = xb @ Wqkv^T + bqkv (unscaled)
    gemm_bt<ushort, true><<<dim3(24, 64, 1), 256, 0, stream>>>(
        xb, Wqkvb, bqkv, QKVb, 1024, 1024, 3072, 1024, 0, 0, 0, 1.0f);

    // V^T for the PV GEMM (V = QKVb columns [2048,3072))
    transpose_v<<<dim3(16, 32, 4), 256, 0, stream>>>(
        QKVb + 2048, Vtb, 3072, 2048L * 3072);

    // scores: per batch [2048,2048] = (Q @ K^T) / 32  (bf16 out)
    gemm_bt<ushort, false><<<dim3(16, 16, 4), 256, 0, stream>>>(
        QKVb, QKVb + 1024, nullptr, Sb, 3072, 3072, 2048, 1024,
        2048L * 3072, 2048L * 3072, 2048L * 2048, 0.03125f);

    // softmax rows, in place
    softmax_rows<<<8192, 256, 0, stream>>>(Sb);

    // O = P @ V : per batch [2048,1024] = Sb @ Vt^T
    gemm_bt<ushort, false><<<dim3(8, 16, 4), 256, 0, stream>>>(
        Sb, Vtb, nullptr, Ob, 2048, 2048, 1024, 2048,
        2048L * 2048, 1024L * 2048, 2048L * 1024, 1.0f);

    // out = O @ Wo^T + bo (fp32)
    gemm_bt<float, true><<<dim3(8, 64, 1), 256, 0, stream>>>(
        Ob, Wob, bo, (float*)d_out, 1024, 1024, 1024, 1024, 0, 0, 0, 1.0f);
}